// Round 14
// baseline (309.649 us; speedup 1.0000x reference)
//
#include <hip/hip_runtime.h>

typedef __bf16 bf16_t;
typedef __bf16 bf16x8 __attribute__((ext_vector_type(8)));
typedef float f32x4 __attribute__((ext_vector_type(4)));

#define MFMA16(a, b, c) __builtin_amdgcn_mfma_f32_16x16x32_bf16(a, b, c, 0, 0, 0)

#define F_W 128
#define ED 512
#define NH 8
#define HD 64
#define NTOK 65536

typedef const __attribute__((address_space(1))) void gvoid_t;
typedef __attribute__((address_space(3))) void lvoid_t;
__device__ __forceinline__ void gload16(const void* g, void* l) {
    __builtin_amdgcn_global_load_lds((gvoid_t*)g, (lvoid_t*)l, 16, 0, 0);
}

// swizzle for [row][32] bf16 tiles (64B rows); 16-row b128 fragment reads on
// this layout measured ZERO conflicts (r7/r8/r13).
__device__ __forceinline__ int swz32(int row) { return ((row >> 1) & 3) << 3; }

// ---------------- prep: weights -> bf16 transposed --------------------------
__global__ __launch_bounds__(256) void prep_kernel(
    const float* __restrict__ qkv_w,   // [512][1536]
    const float* __restrict__ proj_w,  // [512][512]
    bf16_t* __restrict__ qkv_wt,       // [1536][512]
    bf16_t* __restrict__ proj_wt) {    // [512][512]
    int idx = blockIdx.x * 256 + threadIdx.x;
    if (idx < 1536 * 512) {
        int n = idx >> 9, k = idx & 511;
        qkv_wt[idx] = (bf16_t)qkv_w[k * 1536 + n];
    }
    if (idx < 512 * 512) {
        int n = idx >> 9, k = idx & 511;
        proj_wt[idx] = (bf16_t)proj_w[k * 512 + n];
    }
}

// ---------------- prep_x: x fp32 -> bf16 (into d_out scratch) ---------------
__global__ __launch_bounds__(256) void prep_x_kernel(
    const float* __restrict__ x, bf16_t* __restrict__ xbf) {
    size_t i = ((size_t)blockIdx.x * 256 + threadIdx.x) * 8;
    float4 v0 = *(const float4*)(x + i);
    float4 v1 = *(const float4*)(x + i + 4);
    bf16x8 o = {(bf16_t)v0.x, (bf16_t)v0.y, (bf16_t)v0.z, (bf16_t)v0.w,
                (bf16_t)v1.x, (bf16_t)v1.y, (bf16_t)v1.z, (bf16_t)v1.w};
    *(bf16x8*)(xbf + i) = o;
}

// ---------------- K2: QKV GEMM, counted-vmcnt pipeline (T3+T4+T5) -----------
// 256x256 tile, 512 thr / 8 waves (2x4; wave 128x64), 16x16x32 MFMA.
// K=512 as 16 K-halves (32 cols); LDS ring of 4 slots x (A[256][32]+B[256][32])
// = 128 KB. Raw s_barrier (NO vmcnt drain) + counted vmcnt(8) once per K-half;
// staging for slot h+3 issued during K-half h (depth-3 prefetch).
// n-tiles: 0,1 -> Q (x0.125); 2,3 -> K; 4,5 -> V (4 heads each, transposed).
__global__ __launch_bounds__(512, 2) void qkv_gemm_kernel(
    const bf16_t* __restrict__ xbf,     // [NTOK][512] bf16
    const bf16_t* __restrict__ qkv_wt,  // [1536][512] bf16 (n-major)
    const float* __restrict__ qkv_b,    // [1536]
    bf16_t* qk_ws,                      // [NTOK][1024]  Q(scaled)|K
    bf16_t* vt_ws) {                    // [4096][64][128]  V^T per (w,h)
    __shared__ __align__(16) char smem[131072];
    bf16_t* tb = (bf16_t*)smem;             // [256][72] epilogue bounce (aliases)

    const int tid = threadIdx.x;
    const int wave = tid >> 6, lane = tid & 63;
    const int lrow = lane & 15, lgrp = lane >> 4;
    const int wm = wave >> 2;         // 0..1  rows wm*128..+127
    const int wn = wave & 3;          // 0..3  cols wn*64..+63
    const int bid = blockIdx.x;       // [0,1536)
    const int idx = bid >> 3;
    const int mt_l = idx / 6;
    const int nt = idx - mt_l * 6;
    const int mtile = (bid & 7) * 32 + mt_l;   // [0,256) = 2 windows
    const size_t m0 = (size_t)mtile * 256;
    const int n0 = nt * 256;

    // staging: 1KB chunk = 16 rows x 32 bf16; lane -> row lane>>2, seg lane&3
    const int row16 = lane >> 2;
    const int scol = ((lane & 3) * 8) ^ swz32(row16);  // preswizzled source col

    f32x4 acc[8][4];
#pragma unroll
    for (int mf = 0; mf < 8; ++mf)
#pragma unroll
        for (int nf = 0; nf < 4; ++nf) acc[mf][nf] = (f32x4)0.0f;

    // stage A/B subtile of K-half g into ring slot g&3 (2 gload16 each)
    auto stageA = [&](int g) {
        bf16_t* As = (bf16_t*)(smem + (g & 3) * 32768);
        const int k0 = g * 32;
#pragma unroll
        for (int i = 0; i < 2; ++i) {
            int c = wave * 2 + i;
            gload16(xbf + (m0 + c * 16 + row16) * 512 + k0 + scol, As + c * 512);
        }
    };
    auto stageB = [&](int g) {
        bf16_t* Bs = (bf16_t*)(smem + (g & 3) * 32768 + 16384);
        const int k0 = g * 32;
#pragma unroll
        for (int i = 0; i < 2; ++i) {
            int c = wave * 2 + i;
            gload16(qkv_wt + (size_t)(n0 + c * 16 + row16) * 512 + k0 + scol,
                    Bs + c * 512);
        }
    };

    // one K-half: 2 phases; ends after setprio(0) of phase 1 (caller adds
    // the boundary vmcnt + barrier).
    auto khalf = [&](int h) {
        bf16_t* As = (bf16_t*)(smem + (h & 3) * 32768);
        bf16_t* Bs = (bf16_t*)(smem + (h & 3) * 32768 + 16384);
        bf16x8 a[4], b[4];
        // ---- phase 0: a-frags mf 0..3 + all b-frags; stage A of h+3 ----
#pragma unroll
        for (int i = 0; i < 4; ++i) {
            int row = wm * 128 + i * 16 + lrow;
            a[i] = *(const bf16x8*)(As + row * 32 + ((lgrp * 8) ^ swz32(row)));
        }
#pragma unroll
        for (int i = 0; i < 4; ++i) {
            int rw = wn * 64 + i * 16 + lrow;
            b[i] = *(const bf16x8*)(Bs + rw * 32 + ((lgrp * 8) ^ swz32(rw)));
        }
        if (h + 3 < 16) stageA(h + 3);
        __builtin_amdgcn_sched_barrier(0);
        __builtin_amdgcn_s_barrier();
        asm volatile("s_waitcnt lgkmcnt(0)" ::: "memory");
        __builtin_amdgcn_sched_barrier(0);
        __builtin_amdgcn_s_setprio(1);
#pragma unroll
        for (int i = 0; i < 4; ++i)
#pragma unroll
            for (int nf = 0; nf < 4; ++nf)
                acc[i][nf] = MFMA16(a[i], b[nf], acc[i][nf]);
        __builtin_amdgcn_s_setprio(0);
        __builtin_amdgcn_sched_barrier(0);
        __builtin_amdgcn_s_barrier();
        // ---- phase 1: a-frags mf 4..7 (b reused); stage B of h+3 ----
#pragma unroll
        for (int i = 0; i < 4; ++i) {
            int row = wm * 128 + (4 + i) * 16 + lrow;
            a[i] = *(const bf16x8*)(As + row * 32 + ((lgrp * 8) ^ swz32(row)));
        }
        if (h + 3 < 16) stageB(h + 3);
        __builtin_amdgcn_sched_barrier(0);
        __builtin_amdgcn_s_barrier();
        asm volatile("s_waitcnt lgkmcnt(0)" ::: "memory");
        __builtin_amdgcn_sched_barrier(0);
        __builtin_amdgcn_s_setprio(1);
#pragma unroll
        for (int i = 0; i < 4; ++i)
#pragma unroll
            for (int nf = 0; nf < 4; ++nf)
                acc[4 + i][nf] = MFMA16(a[i], b[nf], acc[4 + i][nf]);
        __builtin_amdgcn_s_setprio(0);
        __builtin_amdgcn_sched_barrier(0);
    };

    // prologue: stage slots 0,1,2 (12 loads); slot0 ready when <=8 outstanding
    stageA(0); stageB(0);
    stageA(1); stageB(1);
    stageA(2); stageB(2);
    asm volatile("s_waitcnt vmcnt(8)" ::: "memory");
    __builtin_amdgcn_sched_barrier(0);
    __builtin_amdgcn_s_barrier();

    // main: h=0..12 -> boundary vmcnt(8) (slots h+2,h+3 in flight = 8 loads)
    for (int h = 0; h < 13; ++h) {
        khalf(h);
        asm volatile("s_waitcnt vmcnt(8)" ::: "memory");
        __builtin_amdgcn_sched_barrier(0);
        __builtin_amdgcn_s_barrier();
    }
    khalf(13);   // after h=13: only slot-15 loads (4) newer than slot-14's
    asm volatile("s_waitcnt vmcnt(4)" ::: "memory");
    __builtin_amdgcn_sched_barrier(0);
    __builtin_amdgcn_s_barrier();
    khalf(14);   // nothing newer than slot-15's loads
    asm volatile("s_waitcnt vmcnt(0)" ::: "memory");
    __builtin_amdgcn_sched_barrier(0);
    __builtin_amdgcn_s_barrier();
    khalf(15);
    __builtin_amdgcn_s_barrier();

    // ---------------- epilogue ----------------
    if (nt < 4) {
        // Q or K tile: bias, scale Q, row-major bf16 to qk_ws
        const float scale = (nt < 2) ? 0.125f : 1.0f;
#pragma unroll
        for (int nf = 0; nf < 4; ++nf) {
            int col = n0 + wn * 64 + nf * 16 + lrow;    // [0,1024)
            float bv = qkv_b[col];
#pragma unroll
            for (int mf = 0; mf < 8; ++mf)
#pragma unroll
                for (int j = 0; j < 4; ++j) {
                    int r = wm * 128 + mf * 16 + lgrp * 4 + j;
                    qk_ws[(m0 + r) * 1024 + col] =
                        (bf16_t)((acc[mf][nf][j] + bv) * scale);
                }
        }
    } else {
        // V tile: 4 heads h = (nt-4)*4 + hh; wave wn == hh owns the 64 cols.
#pragma unroll
        for (int hh = 0; hh < 4; ++hh) {
            int h = (nt - 4) * 4 + hh;
            __syncthreads();   // prior LDS use complete
            if (wn == hh) {
#pragma unroll
                for (int nf = 0; nf < 4; ++nf) {
                    int d = nf * 16 + lrow;             // [0,64)
                    float bv = qkv_b[1024 + (nt - 4) * 256 + hh * 64 + d];
#pragma unroll
                    for (int mf = 0; mf < 8; ++mf)
#pragma unroll
                        for (int j = 0; j < 4; ++j) {
                            int r = wm * 128 + mf * 16 + lgrp * 4 + j;
                            tb[r * 72 + d] = (bf16_t)(acc[mf][nf][j] + bv);
                        }
                }
            }
            __syncthreads();
            // transpose-read tb [256][72], write vt_ws[(win*8+h)][d][k]
            {
                int d = tid & 63;
                int kh = tid >> 6;                      // 0..7 -> k = kh*32
#pragma unroll
                for (int o = 0; o < 4; ++o) {
                    int k = kh * 32 + o * 8;            // [0,256)
                    int win = mtile * 2 + (k >> 7);
                    bf16x8 v;
#pragma unroll
                    for (int e = 0; e < 8; ++e)
                        v[e] = tb[(k + e) * 72 + d];
                    *(bf16x8*)(vt_ws + ((size_t)(win * 8 + h) * 64 + d) * 128 +
                               (k & 127)) = v;
                }
            }
        }
    }
}

// ---------------- K3: attention-only, block=(window,head), 512 thr ----------
// (unchanged — proven)
__global__ __launch_bounds__(512, 4) void attn_kernel(
    bf16_t* qk_ws,                      // [NTOK][1024] (Q|K; O -> Q cols)
    const bf16_t* __restrict__ vt_ws,   // [4096][64][128]
    const float* __restrict__ adj) {    // [8][8][128][128]
    __shared__ __align__(16) char sm[32768];
    bf16_t* k_lds  = (bf16_t*)sm;             // [128][64]
    bf16_t* vt_lds = (bf16_t*)(sm + 16384);   // [64][128]
    bf16_t* pbuf   = (bf16_t*)sm;             // [128][40] (aliases k after B)

    const int tid = threadIdx.x;
    const int wave = tid >> 6, lane = tid & 63;
    const int lrow = lane & 15, lgrp = lane >> 4;
    const int bid = blockIdx.x;
    const int w = (bid & 7) * 64 + (bid >> 6);
    const int h = (bid >> 3) & 7;
    const int bidx = bid & 7;

    bf16_t* qrow = qk_ws + (size_t)w * 128 * 1024;

    {
        const int krow_l = lane >> 3;
        const int kcol_l = ((lane & 7) * 8) ^ ((krow_l & 7) << 3);
#pragma unroll
        for (int i = 0; i < 2; ++i) {
            int c = wave * 2 + i;
            gload16(qrow + (size_t)(c * 8 + krow_l) * 1024 + 512 + h * 64 + kcol_l,
                    k_lds + c * 512);
        }
    }
    {
        const bf16_t* vtb = vt_ws + (size_t)(w * 8 + h) * 64 * 128;
        const int vrow_l = lane >> 4;
#pragma unroll
        for (int i = 0; i < 2; ++i) {
            int c = wave * 2 + i;
            int d = c * 4 + vrow_l;
            int vcol = ((lane & 15) * 8) ^ ((d & 7) << 3);
            gload16(vtb + (size_t)d * 128 + vcol, vt_lds + c * 512);
        }
    }
    bf16x8 aq[2];
    {
        int row = wave * 16 + lrow;
#pragma unroll
        for (int kb = 0; kb < 2; ++kb)
            aq[kb] = *(const bf16x8*)(qrow + (size_t)row * 1024 + h * 64 + kb * 32 + lgrp * 8);
    }
    __syncthreads();

    f32x4 sacc[8];
#pragma unroll
    for (int nf = 0; nf < 8; ++nf) sacc[nf] = (f32x4)0.0f;
#pragma unroll
    for (int kb = 0; kb < 2; ++kb) {
        bf16x8 b[8];
#pragma unroll
        for (int nf = 0; nf < 8; ++nf) {
            int row = nf * 16 + lrow;
            b[nf] = *(const bf16x8*)(k_lds + row * 64 + ((kb * 32 + lgrp * 8) ^ ((row & 7) << 3)));
        }
#pragma unroll
        for (int nf = 0; nf < 8; ++nf)
            sacc[nf] = MFMA16(aq[kb], b[nf], sacc[nf]);
    }

    const float* mbase = adj + ((size_t)(bidx * NH + h)) * F_W * F_W;
#pragma unroll
    for (int j = 0; j < 4; ++j) {
        int row = wave * 16 + lgrp * 4 + j;
        const float* mrow = mbase + (size_t)row * F_W;
        float mx = -1e30f;
#pragma unroll
        for (int nf = 0; nf < 8; ++nf) {
            sacc[nf][j] += mrow[nf * 16 + lrow];
            mx = fmaxf(mx, sacc[nf][j]);
        }
#pragma unroll
        for (int d = 1; d < 16; d <<= 1) mx = fmaxf(mx, __shfl_xor(mx, d));
        float sum = 0.f;
#pragma unroll
        for (int nf = 0; nf < 8; ++nf) {
            float p = exp2f((sacc[nf][j] - mx) * 1.44269504f);
            sacc[nf][j] = p;
            sum += p;
        }
#pragma unroll
        for (int d = 1; d < 16; d <<= 1) sum += __shfl_xor(sum, d);
        float r = 1.0f / sum;
#pragma unroll
        for (int nf = 0; nf < 8; ++nf) sacc[nf][j] *= r;
    }
    __syncthreads();

    f32x4 oacc[4];
#pragma unroll
    for (int nf = 0; nf < 4; ++nf) oacc[nf] = (f32x4)0.0f;

#pragma unroll
    for (int kb = 0; kb < 4; ++kb) {
#pragma unroll
        for (int nn = 0; nn < 2; ++nn) {
            int nf = kb * 2 + nn;
            int kk = nn * 16 + lrow;
#pragma unroll
            for (int j = 0; j < 4; ++j) {
                int r = wave * 16 + lgrp * 4 + j;
                pbuf[r * 40 + kk] = (bf16_t)(sacc[nf][j]);
            }
        }
        __syncthreads();
        bf16x8 a = *(const bf16x8*)(pbuf + (wave * 16 + lrow) * 40 + lgrp * 8);
        bf16x8 b[4];
#pragma unroll
        for (int nf = 0; nf < 4; ++nf) {
            int d = nf * 16 + lrow;
            b[nf] = *(const bf16x8*)(vt_lds + d * 128 + ((kb * 32 + lgrp * 8) ^ ((d & 7) << 3)));
        }
#pragma unroll
        for (int nf = 0; nf < 4; ++nf)
            oacc[nf] = MFMA16(a, b[nf], oacc[nf]);
        __syncthreads();
    }

#pragma unroll
    for (int nf = 0; nf < 4; ++nf) {
        int ocol = h * 64 + nf * 16 + lrow;
#pragma unroll
        for (int j = 0; j < 4; ++j) {
            int r = wave * 16 + lgrp * 4 + j;
            qrow[(size_t)r * 1024 + ocol] = (bf16_t)oacc[nf][j];
        }
    }
}

// ---------------- K4: output projection [65536,512]@[512,512]+b -------------
// (r13's conflict-free 128x256 version — unchanged)
__global__ __launch_bounds__(256, 2) void proj_kernel(
    const bf16_t* __restrict__ a_g,   // [NTOK][1024] (cols 0..511 = O)
    const bf16_t* __restrict__ bt_g,  // proj_wt [512][512] (n-major)
    const float* __restrict__ bias,   // [512]
    float* __restrict__ out) {        // [NTOK][512] fp32
    __shared__ __align__(16) char sm_[49152];
    const int tid = threadIdx.x;
    const int wave = tid >> 6, lane = tid & 63;
    const int lrow = lane & 15, lgrp = lane >> 4;
    const int wm = wave >> 1, wn = wave & 1;
    const int bid = blockIdx.x;                  // [0,1024)
    const int idx = bid >> 3;                    // [0,128)
    const int mtile = (bid & 7) * 64 + (idx >> 1);
    const int ntile = idx & 1;
    const size_t m0 = (size_t)mtile * 128;
    const int n0 = ntile * 256;
    const int row16 = lane >> 2;
    const int scol = ((lane & 3) * 8) ^ swz32(row16);

    f32x4 acc[4][8];
#pragma unroll
    for (int mf = 0; mf < 4; ++mf)
#pragma unroll
        for (int nf = 0; nf < 8; ++nf) acc[mf][nf] = (f32x4)0.0f;

    for (int kc = 0; kc < 8; ++kc) {
        const int k0 = kc * 64;
        __syncthreads();
#pragma unroll
        for (int s = 0; s < 2; ++s) {
            bf16_t* As = (bf16_t*)(sm_ + s * 8192);
            bf16_t* Bs = (bf16_t*)(sm_ + 16384 + s * 16384);
#pragma unroll
            for (int i = 0; i < 2; ++i) {
                int c = wave * 2 + i;
                gload16(a_g + (m0 + c * 16 + row16) * 1024 + k0 + s * 32 + scol,
                        As + c * 512);
            }
#pragma unroll
            for (int i = 0; i < 4; ++i) {
                int c = wave * 4 + i;
                gload16(bt_g + (size_t)(n0 + c * 16 + row16) * 512 + k0 + s * 32 + scol,
                        Bs + c * 512);
            }
        }
        __syncthreads();

#pragma unroll
        for (int kb = 0; kb < 2; ++kb) {
            bf16_t* As = (bf16_t*)(sm_ + kb * 8192);
            bf16_t* Bs = (bf16_t*)(sm_ + 16384 + kb * 16384);
            bf16x8 a[4], b[8];
#pragma unroll
            for (int mf = 0; mf < 4; ++mf) {
                int row = wm * 64 + mf * 16 + lrow;
                a[mf] = *(const bf16x8*)(As + row * 32 + ((lgrp * 8) ^ swz32(row)));
            }
#pragma unroll
            for (int nf = 0; nf < 8; ++nf) {
                int rw = wn * 128 + nf * 16 + lrow;
                b[nf] = *(const bf16x8*)(Bs + rw * 32 + ((lgrp * 8) ^ swz32(rw)));
            }
#pragma unroll
            for (int mf = 0; mf < 4; ++mf)
#pragma unroll
                for (int nf = 0; nf < 8; ++nf)
                    acc[mf][nf] = MFMA16(a[mf], b[nf], acc[mf][nf]);
        }
    }

#pragma unroll
    for (int nf = 0; nf < 8; ++nf) {
        int col = n0 + wn * 128 + nf * 16 + lrow;   // [0,512)
        float bv = bias[col];
#pragma unroll
        for (int mf = 0; mf < 4; ++mf)
#pragma unroll
            for (int j = 0; j < 4; ++j) {
                size_t row = m0 + wm * 64 + mf * 16 + lgrp * 4 + j;
                out[row * 512 + col] = acc[mf][nf][j] + bv;
            }
    }
}

extern "C" void kernel_launch(void* const* d_in, const int* in_sizes, int n_in,
                              void* d_out, int out_size, void* d_ws, size_t ws_size,
                              hipStream_t stream) {
    const float* x      = (const float*)d_in[0];
    const float* adj    = (const float*)d_in[1];
    const float* qkv_w  = (const float*)d_in[2];
    const float* qkv_b  = (const float*)d_in[3];
    const float* proj_w = (const float*)d_in[4];
    const float* proj_b = (const float*)d_in[5];
    float* out = (float*)d_out;

    // ws: qk_ws 134.2MB | vt_ws 67.1MB | qkv_wt 1.5MB | proj_wt 0.5MB
    bf16_t* qk_ws   = (bf16_t*)d_ws;
    bf16_t* vt_ws   = qk_ws + (size_t)NTOK * 1024;
    bf16_t* qkv_wt  = vt_ws + (size_t)4096 * 64 * 128;
    bf16_t* proj_wt = qkv_wt + 1536 * 512;
    // x-bf16 lives in d_out (64MB of its 128MB); proj overwrites d_out last.
    bf16_t* xbf = (bf16_t*)d_out;

    prep_kernel<<<3072, 256, 0, stream>>>(qkv_w, proj_w, qkv_wt, proj_wt);
    prep_x_kernel<<<NTOK * ED / 8 / 256, 256, 0, stream>>>(x, xbf);
    qkv_gemm_kernel<<<1536, 512, 0, stream>>>(xbf, qkv_wt, qkv_b, qk_ws, vt_ws);
    attn_kernel<<<4096, 512, 0, stream>>>(qk_ws, vt_ws, adj);
    proj_kernel<<<1024, 256, 0, stream>>>(qk_ws, proj_wt, proj_b, out);
}

// Round 15
// 289.550 us; speedup vs baseline: 1.0694x; 1.0694x over previous
//
#include <hip/hip_runtime.h>

typedef __bf16 bf16_t;
typedef __bf16 bf16x8 __attribute__((ext_vector_type(8)));
typedef float f32x4 __attribute__((ext_vector_type(4)));
typedef float f32x16 __attribute__((ext_vector_type(16)));

#define MFMA16(a, b, c) __builtin_amdgcn_mfma_f32_16x16x32_bf16(a, b, c, 0, 0, 0)
#define MFMA32(a, b, c) __builtin_amdgcn_mfma_f32_32x32x16_bf16(a, b, c, 0, 0, 0)

#define F_W 128
#define ED 512
#define NH 8
#define HD 64
#define NTOK 65536

typedef const __attribute__((address_space(1))) void gvoid_t;
typedef __attribute__((address_space(3))) void lvoid_t;
__device__ __forceinline__ void gload16(const void* g, void* l) {
    __builtin_amdgcn_global_load_lds((gvoid_t*)g, (lvoid_t*)l, 16, 0, 0);
}

// swizzle for [row][32] bf16 tiles (64B rows); 16-row b128 reads = 0 conflicts
__device__ __forceinline__ int swz32(int row) { return ((row >> 1) & 3) << 3; }

// ---------------- prep (merged): x->bf16 + weights->bf16 transposed ---------
__global__ __launch_bounds__(256) void prep_all_kernel(
    const float* __restrict__ x,       // [NTOK][512]
    const float* __restrict__ qkv_w,   // [512][1536]
    const float* __restrict__ proj_w,  // [512][512]
    bf16_t* __restrict__ xbf,          // [NTOK][512]
    bf16_t* __restrict__ qkv_wt,       // [1536][512]
    bf16_t* __restrict__ proj_wt) {    // [512][512]
    int gid = blockIdx.x * 256 + threadIdx.x;
    size_t i = (size_t)gid * 8;
    float4 v0 = *(const float4*)(x + i);
    float4 v1 = *(const float4*)(x + i + 4);
    bf16x8 o = {(bf16_t)v0.x, (bf16_t)v0.y, (bf16_t)v0.z, (bf16_t)v0.w,
                (bf16_t)v1.x, (bf16_t)v1.y, (bf16_t)v1.z, (bf16_t)v1.w};
    *(bf16x8*)(xbf + i) = o;
    if (gid < 1536 * 512) {
        int n = gid >> 9, k = gid & 511;
        qkv_wt[gid] = (bf16_t)qkv_w[k * 1536 + n];
    }
    if (gid < 512 * 512) {
        int n = gid >> 9, k = gid & 511;
        proj_wt[gid] = (bf16_t)proj_w[k * 512 + n];
    }
}

// ---------------- K2: QKV GEMM [65536,512]x[512,1536] (r10, best) -----------
// 128x128 tiles, 2x2 wave grid (wave 64x64), 32x32x16 MFMA, BK=64,
// single-buffered [128][64]-swz8 tiles (32 KB), 8 K-steps, 4 blocks/CU.
// n-tiles 0..3 -> Q (x0.125), 4..7 -> K, 8..11 -> V (transposed to vt_ws).
__global__ __launch_bounds__(256, 4) void qkv_gemm_kernel(
    const bf16_t* __restrict__ xbf,     // [NTOK][512] bf16
    const bf16_t* __restrict__ qkv_wt,  // [1536][512] bf16 (n-major)
    const float* __restrict__ qkv_b,    // [1536]
    bf16_t* qk_ws,                      // [NTOK][1024]  Q(scaled)|K
    bf16_t* vt_ws) {                    // [4096][64][128]  V^T per (w,h)
    __shared__ __align__(16) char sm[32768];
    bf16_t* x_s = (bf16_t*)sm;              // [128][64] swz8
    bf16_t* w_s = (bf16_t*)(sm + 16384);    // [128][64] swz8
    bf16_t* tb  = (bf16_t*)sm;              // [128][72] epilogue bounce (aliases)

    const int tid = threadIdx.x;
    const int wave = tid >> 6, lane = tid & 63;
    const int l31 = lane & 31, lhi = lane >> 5;
    const int wm = wave >> 1, wn = wave & 1;
    const int bid = blockIdx.x;
    const int idx = bid >> 3;
    const int mt_l = idx / 12;
    const int nt = idx - mt_l * 12;
    const int mtile = (bid & 7) * 64 + mt_l;   // == window index
    const size_t m0 = (size_t)mtile * 128;
    const int n0 = nt * 128;

    // staging: 1KB chunk = 8 rows x 64 bf16; lane -> row lane>>3, col (lane&7)*8
    const int srow = lane >> 3;
    const int scol = ((lane & 7) * 8) ^ ((srow & 7) << 3);  // preswizzled src col

    f32x16 acc[2][2];
#pragma unroll
    for (int mf = 0; mf < 2; ++mf)
#pragma unroll
        for (int nf = 0; nf < 2; ++nf) acc[mf][nf] = (f32x16)0.0f;

    for (int kc = 0; kc < 8; ++kc) {
        const int k0 = kc * 64;
        __syncthreads();   // previous compute's reads done
#pragma unroll
        for (int i = 0; i < 4; ++i) {  // x: 16 chunks of 8 rows
            int c = wave * 4 + i;
            gload16(xbf + (m0 + c * 8 + srow) * 512 + k0 + scol, x_s + c * 512);
        }
#pragma unroll
        for (int i = 0; i < 4; ++i) {  // w: 16 chunks of 8 rows
            int c = wave * 4 + i;
            gload16(qkv_wt + (size_t)(n0 + c * 8 + srow) * 512 + k0 + scol,
                    w_s + c * 512);
        }
        __syncthreads();   // staged data visible

#pragma unroll
        for (int ks = 0; ks < 4; ++ks) {  // 4 x (K=16)
            bf16x8 a[2], b[2];
#pragma unroll
            for (int mf = 0; mf < 2; ++mf) {
                int row = wm * 64 + mf * 32 + l31;
                a[mf] = *(const bf16x8*)(x_s + row * 64 +
                                         ((ks * 16 + lhi * 8) ^ ((row & 7) << 3)));
            }
#pragma unroll
            for (int nf = 0; nf < 2; ++nf) {
                int rw = wn * 64 + nf * 32 + l31;
                b[nf] = *(const bf16x8*)(w_s + rw * 64 +
                                         ((ks * 16 + lhi * 8) ^ ((rw & 7) << 3)));
            }
#pragma unroll
            for (int mf = 0; mf < 2; ++mf)
#pragma unroll
                for (int nf = 0; nf < 2; ++nf)
                    acc[mf][nf] = MFMA32(a[mf], b[nf], acc[mf][nf]);
        }
    }

    if (nt < 8) {
        // Q or K tile: bias, scale Q, row-major bf16 to qk_ws
        // D layout (32x32): col = lane&31, row = (j&3) + 8*(j>>2) + 4*(lane>>5)
        const float scale = (nt < 4) ? 0.125f : 1.0f;
#pragma unroll
        for (int nf = 0; nf < 2; ++nf) {
            int col = n0 + wn * 64 + nf * 32 + l31;    // [0,1024)
            float bv = qkv_b[col];
#pragma unroll
            for (int mf = 0; mf < 2; ++mf)
#pragma unroll
                for (int j = 0; j < 16; ++j) {
                    int r = wm * 64 + mf * 32 + (j & 3) + 8 * (j >> 2) + 4 * lhi;
                    qk_ws[(m0 + r) * 1024 + col] =
                        (bf16_t)((acc[mf][nf][j] + bv) * scale);
                }
        }
    } else {
        // V tile: wave wn owns head (nt-8)*2 + wn (cols wn*64..+63 of tile)
#pragma unroll
        for (int hh = 0; hh < 2; ++hh) {
            int h = (nt - 8) * 2 + hh;
            __syncthreads();   // prior sm reads (or prior tb pass) complete
            if (wn == hh) {
#pragma unroll
                for (int nf = 0; nf < 2; ++nf) {
                    int d = nf * 32 + l31;             // [0,64)
                    float bv = qkv_b[n0 + hh * 64 + d];
#pragma unroll
                    for (int mf = 0; mf < 2; ++mf)
#pragma unroll
                        for (int j = 0; j < 16; ++j) {
                            int r = wm * 64 + mf * 32 + (j & 3) + 8 * (j >> 2) + 4 * lhi;
                            tb[r * 72 + d] = (bf16_t)(acc[mf][nf][j] + bv);
                        }
                }
            }
            __syncthreads();
            // transpose-read, coalesced write: vt_ws[(mtile*8+h)][d][k]
            {
                int d = tid & 63;
                int kh = tid >> 6;                     // k range kh*32
                bf16_t* outp = vt_ws + ((size_t)(mtile * 8 + h) * 64 + d) * 128 + kh * 32;
#pragma unroll
                for (int o = 0; o < 4; ++o) {
                    bf16x8 v;
#pragma unroll
                    for (int e = 0; e < 8; ++e)
                        v[e] = tb[(kh * 32 + o * 8 + e) * 72 + d];
                    *(bf16x8*)(outp + o * 8) = v;
                }
            }
        }
    }
}

// ---------------- K3: attention-only, block=(window,head), 512 thr ----------
// r10 base + PV ping-pong: two 8KB P-buffers (stride-32 swz32, conflict-free
// 16-row reads); write-next-chunk overlapped with current MFMA; 5 barriers.
__global__ __launch_bounds__(512, 4) void attn_kernel(
    bf16_t* qk_ws,                      // [NTOK][1024] (Q|K; O -> Q cols)
    const bf16_t* __restrict__ vt_ws,   // [4096][64][128]
    const float* __restrict__ adj) {    // [8][8][128][128]
    __shared__ __align__(16) char sm[32768];
    bf16_t* k_lds  = (bf16_t*)sm;             // [128][64]
    bf16_t* vt_lds = (bf16_t*)(sm + 16384);   // [64][128]
    bf16_t* pb0    = (bf16_t*)sm;             // [128][32] swz32 (aliases k)
    bf16_t* pb1    = (bf16_t*)(sm + 8192);    // [128][32] swz32

    const int tid = threadIdx.x;
    const int wave = tid >> 6, lane = tid & 63;
    const int lrow = lane & 15, lgrp = lane >> 4;
    const int bid = blockIdx.x;
    const int w = (bid & 7) * 64 + (bid >> 6);
    const int h = (bid >> 3) & 7;
    const int bidx = bid & 7;

    bf16_t* qrow = qk_ws + (size_t)w * 128 * 1024;

    {
        const int krow_l = lane >> 3;
        const int kcol_l = ((lane & 7) * 8) ^ ((krow_l & 7) << 3);
#pragma unroll
        for (int i = 0; i < 2; ++i) {
            int c = wave * 2 + i;
            gload16(qrow + (size_t)(c * 8 + krow_l) * 1024 + 512 + h * 64 + kcol_l,
                    k_lds + c * 512);
        }
    }
    {
        const bf16_t* vtb = vt_ws + (size_t)(w * 8 + h) * 64 * 128;
        const int vrow_l = lane >> 4;
#pragma unroll
        for (int i = 0; i < 2; ++i) {
            int c = wave * 2 + i;
            int d = c * 4 + vrow_l;
            int vcol = ((lane & 15) * 8) ^ ((d & 7) << 3);
            gload16(vtb + (size_t)d * 128 + vcol, vt_lds + c * 512);
        }
    }
    bf16x8 aq[2];
    {
        int row = wave * 16 + lrow;
#pragma unroll
        for (int kb = 0; kb < 2; ++kb)
            aq[kb] = *(const bf16x8*)(qrow + (size_t)row * 1024 + h * 64 + kb * 32 + lgrp * 8);
    }
    __syncthreads();

    f32x4 sacc[8];
#pragma unroll
    for (int nf = 0; nf < 8; ++nf) sacc[nf] = (f32x4)0.0f;
#pragma unroll
    for (int kb = 0; kb < 2; ++kb) {
        bf16x8 b[8];
#pragma unroll
        for (int nf = 0; nf < 8; ++nf) {
            int row = nf * 16 + lrow;
            b[nf] = *(const bf16x8*)(k_lds + row * 64 + ((kb * 32 + lgrp * 8) ^ ((row & 7) << 3)));
        }
#pragma unroll
        for (int nf = 0; nf < 8; ++nf)
            sacc[nf] = MFMA16(aq[kb], b[nf], sacc[nf]);
    }

    const float* mbase = adj + ((size_t)(bidx * NH + h)) * F_W * F_W;
#pragma unroll
    for (int j = 0; j < 4; ++j) {
        int row = wave * 16 + lgrp * 4 + j;
        const float* mrow = mbase + (size_t)row * F_W;
        float mx = -1e30f;
#pragma unroll
        for (int nf = 0; nf < 8; ++nf) {
            sacc[nf][j] += mrow[nf * 16 + lrow];
            mx = fmaxf(mx, sacc[nf][j]);
        }
#pragma unroll
        for (int d = 1; d < 16; d <<= 1) mx = fmaxf(mx, __shfl_xor(mx, d));
        float sum = 0.f;
#pragma unroll
        for (int nf = 0; nf < 8; ++nf) {
            float p = exp2f((sacc[nf][j] - mx) * 1.44269504f);
            sacc[nf][j] = p;
            sum += p;
        }
#pragma unroll
        for (int d = 1; d < 16; d <<= 1) sum += __shfl_xor(sum, d);
        float r = 1.0f / sum;
#pragma unroll
        for (int nf = 0; nf < 8; ++nf) sacc[nf][j] *= r;
    }
    __syncthreads();   // k_lds dead; pb0/pb1 may be written

    // write P chunk 0 (K cols 0..31) into pb0
#pragma unroll
    for (int nn = 0; nn < 2; ++nn) {
        int kk = nn * 16 + lrow;
#pragma unroll
        for (int j = 0; j < 4; ++j) {
            int r = wave * 16 + lgrp * 4 + j;
            pb0[r * 32 + (kk ^ swz32(r))] = (bf16_t)(sacc[nn][j]);
        }
    }
    __syncthreads();

    f32x4 oacc[4];
#pragma unroll
    for (int nf = 0; nf < 4; ++nf) oacc[nf] = (f32x4)0.0f;

#pragma unroll
    for (int kb = 0; kb < 4; ++kb) {
        bf16_t* pcur = (kb & 1) ? pb1 : pb0;
        bf16_t* pnxt = (kb & 1) ? pb0 : pb1;
        // read current P fragment (16-row swz32 pattern, 0-conflict)
        int arow = wave * 16 + lrow;
        bf16x8 a = *(const bf16x8*)(pcur + arow * 32 + ((lgrp * 8) ^ swz32(arow)));
        // overlap: write next chunk while current MFMA issues
        if (kb < 3) {
#pragma unroll
            for (int nn = 0; nn < 2; ++nn) {
                int nf = (kb + 1) * 2 + nn;
                int kk = nn * 16 + lrow;
#pragma unroll
                for (int j = 0; j < 4; ++j) {
                    int r = wave * 16 + lgrp * 4 + j;
                    pnxt[r * 32 + (kk ^ swz32(r))] = (bf16_t)(sacc[nf][j]);
                }
            }
        }
        bf16x8 b[4];
#pragma unroll
        for (int nf = 0; nf < 4; ++nf) {
            int d = nf * 16 + lrow;
            b[nf] = *(const bf16x8*)(vt_lds + d * 128 + ((kb * 32 + lgrp * 8) ^ ((d & 7) << 3)));
        }
#pragma unroll
        for (int nf = 0; nf < 4; ++nf)
            oacc[nf] = MFMA16(a, b[nf], oacc[nf]);
        __syncthreads();
    }

#pragma unroll
    for (int nf = 0; nf < 4; ++nf) {
        int ocol = h * 64 + nf * 16 + lrow;
#pragma unroll
        for (int j = 0; j < 4; ++j) {
            int r = wave * 16 + lgrp * 4 + j;
            qrow[(size_t)r * 1024 + ocol] = (bf16_t)oacc[nf][j];
        }
    }
}

// ---------------- K4: output projection (r10, best) -------------------------
// 128-tile, 32x32x16 MFMA, [128][64]-swz8, BK=64 single-buffered.
__global__ __launch_bounds__(256, 4) void proj_kernel(
    const bf16_t* __restrict__ a_g,   // [NTOK][1024] (cols 0..511 = O)
    const bf16_t* __restrict__ bt_g,  // proj_wt [512][512] (n-major)
    const float* __restrict__ bias,   // [512]
    float* __restrict__ out) {        // [NTOK][512] fp32
    __shared__ __align__(16) char sm_[32768];
    bf16_t* a_s = (bf16_t*)sm_;             // [128][64] swz8
    bf16_t* b_s = (bf16_t*)(sm_ + 16384);   // [128][64] swz8
    const int tid = threadIdx.x;
    const int wave = tid >> 6, lane = tid & 63;
    const int l31 = lane & 31, lhi = lane >> 5;
    const int wm = wave >> 1, wn = wave & 1;
    const int bid = blockIdx.x;                        // [0,2048)
    const int mtile = (bid & 7) * 64 + (bid >> 5);
    const int ntile = (bid >> 3) & 3;
    const size_t m0 = (size_t)mtile * 128;
    const int n0 = ntile * 128;
    const int srow = lane >> 3;
    const int scol = ((lane & 7) * 8) ^ ((srow & 7) << 3);

    f32x16 acc[2][2];
#pragma unroll
    for (int mf = 0; mf < 2; ++mf)
#pragma unroll
        for (int nf = 0; nf < 2; ++nf) acc[mf][nf] = (f32x16)0.0f;

    for (int kc = 0; kc < 8; ++kc) {
        const int k0 = kc * 64;
        __syncthreads();
#pragma unroll
        for (int i = 0; i < 4; ++i) {
            int c = wave * 4 + i;
            gload16(a_g + (m0 + c * 8 + srow) * 1024 + k0 + scol, a_s + c * 512);
            gload16(bt_g + (size_t)(n0 + c * 8 + srow) * 512 + k0 + scol, b_s + c * 512);
        }
        __syncthreads();

#pragma unroll
        for (int ks = 0; ks < 4; ++ks) {
            bf16x8 a[2], b[2];
#pragma unroll
            for (int mf = 0; mf < 2; ++mf) {
                int row = wm * 64 + mf * 32 + l31;
                a[mf] = *(const bf16x8*)(a_s + row * 64 +
                                         ((ks * 16 + lhi * 8) ^ ((row & 7) << 3)));
            }
#pragma unroll
            for (int nf = 0; nf < 2; ++nf) {
                int rw = wn * 64 + nf * 32 + l31;
                b[nf] = *(const bf16x8*)(b_s + rw * 64 +
                                         ((ks * 16 + lhi * 8) ^ ((rw & 7) << 3)));
            }
#pragma unroll
            for (int mf = 0; mf < 2; ++mf)
#pragma unroll
                for (int nf = 0; nf < 2; ++nf)
                    acc[mf][nf] = MFMA32(a[mf], b[nf], acc[mf][nf]);
        }
    }

#pragma unroll
    for (int nf = 0; nf < 2; ++nf) {
        int col = n0 + wn * 64 + nf * 32 + l31;
        float bv = bias[col];
#pragma unroll
        for (int mf = 0; mf < 2; ++mf)
#pragma unroll
            for (int j = 0; j < 16; ++j) {
                size_t row = m0 + wm * 64 + mf * 32 + (j & 3) + 8 * (j >> 2) + 4 * lhi;
                out[row * 512 + col] = acc[mf][nf][j] + bv;
            }
    }
}

extern "C" void kernel_launch(void* const* d_in, const int* in_sizes, int n_in,
                              void* d_out, int out_size, void* d_ws, size_t ws_size,
                              hipStream_t stream) {
    const float* x      = (const float*)d_in[0];
    const float* adj    = (const float*)d_in[1];
    const float* qkv_w  = (const float*)d_in[2];
    const float* qkv_b  = (const float*)d_in[3];
    const float* proj_w = (const float*)d_in[4];
    const float* proj_b = (const float*)d_in[5];
    float* out = (float*)d_out;

    // ws: qk_ws 134.2MB | vt_ws 67.1MB | qkv_wt 1.5MB | proj_wt 0.5MB
    bf16_t* qk_ws   = (bf16_t*)d_ws;
    bf16_t* vt_ws   = qk_ws + (size_t)NTOK * 1024;
    bf16_t* qkv_wt  = vt_ws + (size_t)4096 * 64 * 128;
    bf16_t* proj_wt = qkv_wt + 1536 * 512;
    // x-bf16 lives in d_out (64MB of its 128MB); proj overwrites d_out last.
    bf16_t* xbf = (bf16_t*)d_out;

    prep_all_kernel<<<NTOK * ED / 8 / 256, 256, 0, stream>>>(
        x, qkv_w, proj_w, xbf, qkv_wt, proj_wt);
    qkv_gemm_kernel<<<6144, 256, 0, stream>>>(xbf, qkv_wt, qkv_b, qk_ws, vt_ws);
    attn_kernel<<<4096, 512, 0, stream>>>(qk_ws, vt_ws, adj);
    proj_kernel<<<2048, 256, 0, stream>>>(qk_ws, proj_wt, proj_b, out);
}